// Round 4
// baseline (608.564 us; speedup 1.0000x reference)
//
#include <hip/hip_runtime.h>
#include <stdint.h>

#define BLOCK 256

// ---------------------------------------------------------------------------
// ws layout:
//   [0..3]    nsat counter
//   [4..7]    done ticket
//   [64 ..)   predbits  : 1 bit per var,   ((n_vars+63)/64)*8 bytes (~128 KB)
//   [satoff..) satmap   : 1 bit per clause, ((n_clauses+31)/32)*4 bytes (~512 KB)
// Everything re-zeroed / fully overwritten by prep() each call (ws is poisoned
// to 0xAA before every timed launch).
// ---------------------------------------------------------------------------

__global__ void prep(const float* __restrict__ preds,
                     unsigned long long* __restrict__ predbits,
                     uint4* __restrict__ satz,
                     unsigned* __restrict__ hdr,
                     int n_vars,
                     const int* __restrict__ nc_p) {
    const int gid = blockIdx.x * blockDim.x + threadIdx.x;
    const int stride = gridDim.x * blockDim.x;

    // pack preds -> 1 bit per var (wave-uniform loop bound; blockDim % 64 == 0)
    const int nv64 = (n_vars + 63) & ~63;
    for (int i = gid; i < nv64; i += stride) {
        const bool b = (i < n_vars) && (preds[i] >= 0.5f);
        const unsigned long long m = __ballot(b);
        if ((threadIdx.x & 63) == 0) predbits[i >> 6] = m;
    }

    // zero the clause-sat bitmap
    const int nc = *nc_p;
    const int satw16 = (((nc + 31) >> 5) + 3) >> 2;   // uint4 count
    const uint4 z = {0u, 0u, 0u, 0u};
    for (int i = gid; i < satw16; i += stride) satz[i] = z;

    if (gid == 0) { hdr[0] = 0u; hdr[1] = 0u; }
}

__device__ __forceinline__ void edge_one(int lit, int cls, int nv,
                                         const unsigned* __restrict__ predbits,
                                         unsigned* __restrict__ sat) {
    const bool pos = lit < nv;
    const int v = pos ? lit : lit - nv;
    const unsigned pb = predbits[v >> 5];
    const bool pbit = ((pb >> (v & 31)) & 1u) != 0u;
    if (pbit == pos) {                       // literal satisfied
        const unsigned w = ((unsigned)cls) >> 5;
        const unsigned m = 1u << (cls & 31);
        if ((sat[w] & m) == 0u)              // cheap L2-resident pre-check
            atomicOr(&sat[w], m);
    }
}

__global__ void scatter_sat(const int* __restrict__ lits,
                            const int* __restrict__ clauses,
                            const unsigned* __restrict__ predbits,
                            unsigned* __restrict__ sat,
                            int n_edges, int n_vars) {
    const int tid = blockIdx.x * blockDim.x + threadIdx.x;
    const int stride = gridDim.x * blockDim.x;
    const int n4 = n_edges >> 2;

    const int4* __restrict__ l4 = reinterpret_cast<const int4*>(lits);
    const int4* __restrict__ c4 = reinterpret_cast<const int4*>(clauses);

    for (int i = tid; i < n4; i += stride) {
        const int4 l = l4[i];
        const int4 c = c4[i];
        edge_one(l.x, c.x, n_vars, predbits, sat);
        edge_one(l.y, c.y, n_vars, predbits, sat);
        edge_one(l.z, c.z, n_vars, predbits, sat);
        edge_one(l.w, c.w, n_vars, predbits, sat);
    }
    for (int i = (n4 << 2) + tid; i < n_edges; i += stride) {
        edge_one(lits[i], clauses[i], n_vars, predbits, sat);
    }
}

__global__ void reduce_finalize(const uint4* __restrict__ sat16,
                                unsigned* __restrict__ nsat,
                                unsigned* __restrict__ done,
                                float* __restrict__ out,
                                const int* __restrict__ nc_p,
                                int n_vars) {
    const int nc = *nc_p;
    const int n16 = (((nc + 31) >> 5) + 3) >> 2;
    const int tid = blockIdx.x * blockDim.x + threadIdx.x;
    const int stride = gridDim.x * blockDim.x;

    unsigned acc = 0;
    for (int i = tid; i < n16; i += stride) {
        const uint4 v = sat16[i];
        acc += __popc(v.x) + __popc(v.y) + __popc(v.z) + __popc(v.w);
    }

    #pragma unroll
    for (int off = 32; off > 0; off >>= 1) acc += __shfl_down(acc, off);

    __shared__ unsigned smem[BLOCK / 64];
    const int lane = threadIdx.x & 63;
    const int wid  = threadIdx.x >> 6;
    if (lane == 0) smem[wid] = acc;
    __syncthreads();

    if (threadIdx.x == 0) {
        unsigned bsum = 0;
        #pragma unroll
        for (int w = 0; w < BLOCK / 64; ++w) bsum += smem[w];
        atomicAdd(nsat, bsum);
        __threadfence();
        const unsigned ticket = atomicAdd(done, 1u);
        if (ticket == (unsigned)(gridDim.x - 1)) {
            const unsigned total = atomicAdd(nsat, 0u);
            *out = ((float)nc - (float)total) / (float)n_vars;
        }
    }
}

extern "C" void kernel_launch(void* const* d_in, const int* in_sizes, int n_in,
                              void* d_out, int out_size, void* d_ws, size_t ws_size,
                              hipStream_t stream) {
    const float* preds   = (const float*)d_in[0];
    const int*   lits    = (const int*)d_in[1];
    const int*   clauses = (const int*)d_in[2];
    const int*   nc_p    = (const int*)d_in[4];   // n_clauses (device scalar)
    const int    n_vars  = in_sizes[0];
    const int    n_edges = in_sizes[1];

    float* out = (float*)d_out;
    unsigned char* ws = (unsigned char*)d_ws;
    unsigned* hdr = (unsigned*)ws;                 // [0]=nsat, [1]=done
    unsigned long long* predbits = (unsigned long long*)(ws + 64);
    const size_t predbits_bytes = ((size_t)((n_vars + 63) / 64)) * 8;
    size_t satoff = 64 + predbits_bytes;
    satoff = (satoff + 15) & ~(size_t)15;          // 16B align for uint4 ops
    unsigned* satmap = (unsigned*)(ws + satoff);

    prep<<<2048, BLOCK, 0, stream>>>(preds, predbits, (uint4*)satmap, hdr,
                                     n_vars, nc_p);
    scatter_sat<<<2048, BLOCK, 0, stream>>>(lits, clauses,
                                            (const unsigned*)predbits, satmap,
                                            n_edges, n_vars);
    reduce_finalize<<<128, BLOCK, 0, stream>>>((const uint4*)satmap,
                                               hdr, hdr + 1, out, nc_p, n_vars);
}

// Round 5
// 272.945 us; speedup vs baseline: 2.2296x; 2.2296x over previous
//
#include <hip/hip_runtime.h>
#include <stdint.h>

#define BLOCK 256

typedef int iv4 __attribute__((ext_vector_type(4)));

// ---------------------------------------------------------------------------
// ws layout:
//   [0..3]     nsat counter
//   [4..7]     done ticket
//   [64 ..)    predbits : 1 bit per var, ((n_vars+63)/64)*8 bytes (~128 KB)
//   [satoff..) sat      : 1 BYTE per clause (~4 MB), plain stores (no atomics)
// Everything rebuilt每 call (ws re-poisoned to 0xAA before every timed launch).
// ---------------------------------------------------------------------------

__global__ void prep(const float* __restrict__ preds,
                     unsigned long long* __restrict__ predbits,
                     uint4* __restrict__ satz,
                     unsigned* __restrict__ hdr,
                     int n_vars,
                     const int* __restrict__ nc_p) {
    const int gid = blockIdx.x * blockDim.x + threadIdx.x;
    const int stride = gridDim.x * blockDim.x;

    // pack preds -> 1 bit per var (NT read: preds is single-use here)
    const int nv64 = (n_vars + 63) & ~63;
    for (int i = gid; i < nv64; i += stride) {
        bool b = false;
        if (i < n_vars) b = (__builtin_nontemporal_load(&preds[i]) >= 0.5f);
        const unsigned long long m = __ballot(b);
        if ((threadIdx.x & 63) == 0) predbits[i >> 6] = m;
    }

    // zero the clause-sat byte array (16B granularity)
    const int nc = *nc_p;
    const int satw16 = (nc + 15) >> 4;          // uint4 count
    const uint4 z = {0u, 0u, 0u, 0u};
    for (int i = gid; i < satw16; i += stride) satz[i] = z;

    if (gid == 0) { hdr[0] = 0u; hdr[1] = 0u; }
}

__device__ __forceinline__ void edge_one(int lit, int cls, int nv,
                                         const unsigned* __restrict__ predbits,
                                         unsigned char* __restrict__ sat) {
    const bool pos = lit < nv;
    const int v = pos ? lit : lit - nv;
    const unsigned pb = predbits[v >> 5];            // L2-resident 128 KB
    const bool pbit = ((pb >> (v & 31)) & 1u) != 0u;
    if (pbit == pos) sat[cls] = (unsigned char)1;    // plain store, benign race
}

__global__ void scatter_sat(const int* __restrict__ lits,
                            const int* __restrict__ clauses,
                            const unsigned* __restrict__ predbits,
                            unsigned char* __restrict__ sat,
                            int n_edges, int n_vars) {
    const int tid = blockIdx.x * blockDim.x + threadIdx.x;
    const int stride = gridDim.x * blockDim.x;
    const int n4 = n_edges >> 2;

    const iv4* __restrict__ l4 = reinterpret_cast<const iv4*>(lits);
    const iv4* __restrict__ c4 = reinterpret_cast<const iv4*>(clauses);

    for (int i = tid; i < n4; i += stride) {
        // non-temporal stream loads: keep L2 free for sat + predbits
        const iv4 l = __builtin_nontemporal_load(&l4[i]);
        const iv4 c = __builtin_nontemporal_load(&c4[i]);
        edge_one(l.x, c.x, n_vars, predbits, sat);
        edge_one(l.y, c.y, n_vars, predbits, sat);
        edge_one(l.z, c.z, n_vars, predbits, sat);
        edge_one(l.w, c.w, n_vars, predbits, sat);
    }
    for (int i = (n4 << 2) + tid; i < n_edges; i += stride) {
        edge_one(lits[i], clauses[i], n_vars, predbits, sat);
    }
}

__global__ void reduce_finalize(const uint4* __restrict__ sat16,
                                unsigned* __restrict__ nsat,
                                unsigned* __restrict__ done,
                                float* __restrict__ out,
                                const int* __restrict__ nc_p,
                                int n_vars) {
    const int nc = *nc_p;
    const int n16 = (nc + 15) >> 4;     // sat bytes are 0/1; padded region zeroed
    const int tid = blockIdx.x * blockDim.x + threadIdx.x;
    const int stride = gridDim.x * blockDim.x;

    unsigned acc = 0;
    for (int i = tid; i < n16; i += stride) {
        const uint4 v = sat16[i];
        acc += __popc(v.x & 0x01010101u) + __popc(v.y & 0x01010101u) +
               __popc(v.z & 0x01010101u) + __popc(v.w & 0x01010101u);
    }

    #pragma unroll
    for (int off = 32; off > 0; off >>= 1) acc += __shfl_down(acc, off);

    __shared__ unsigned smem[BLOCK / 64];
    const int lane = threadIdx.x & 63;
    const int wid  = threadIdx.x >> 6;
    if (lane == 0) smem[wid] = acc;
    __syncthreads();

    if (threadIdx.x == 0) {
        unsigned bsum = 0;
        #pragma unroll
        for (int w = 0; w < BLOCK / 64; ++w) bsum += smem[w];
        atomicAdd(nsat, bsum);
        __threadfence();
        const unsigned ticket = atomicAdd(done, 1u);
        if (ticket == (unsigned)(gridDim.x - 1)) {
            const unsigned total = atomicAdd(nsat, 0u);
            *out = ((float)nc - (float)total) / (float)n_vars;
        }
    }
}

extern "C" void kernel_launch(void* const* d_in, const int* in_sizes, int n_in,
                              void* d_out, int out_size, void* d_ws, size_t ws_size,
                              hipStream_t stream) {
    const float* preds   = (const float*)d_in[0];
    const int*   lits    = (const int*)d_in[1];
    const int*   clauses = (const int*)d_in[2];
    const int*   nc_p    = (const int*)d_in[4];   // n_clauses (device scalar)
    const int    n_vars  = in_sizes[0];
    const int    n_edges = in_sizes[1];

    float* out = (float*)d_out;
    unsigned char* ws = (unsigned char*)d_ws;
    unsigned* hdr = (unsigned*)ws;                 // [0]=nsat, [1]=done
    unsigned long long* predbits = (unsigned long long*)(ws + 64);
    const size_t predbits_bytes = ((size_t)((n_vars + 63) / 64)) * 8;
    size_t satoff = 64 + predbits_bytes;
    satoff = (satoff + 63) & ~(size_t)63;          // 64B align sat array
    unsigned char* sat = ws + satoff;

    prep<<<2048, BLOCK, 0, stream>>>(preds, predbits, (uint4*)sat, hdr,
                                     n_vars, nc_p);
    scatter_sat<<<2048, BLOCK, 0, stream>>>(lits, clauses,
                                            (const unsigned*)predbits, sat,
                                            n_edges, n_vars);
    reduce_finalize<<<256, BLOCK, 0, stream>>>((const uint4*)sat,
                                               hdr, hdr + 1, out, nc_p, n_vars);
}